// Round 2
// baseline (10670.182 us; speedup 1.0000x reference)
//
#include <hip/hip_runtime.h>

// ---- problem constants ----
#define T_LEN   240
#define B_SZ    8
#define NFILT   2560
#define KD      9216          // 96*96
#define M_DIM   1920          // B*T
#define N_DIM   5120          // 2*NF (sin | cos)
#define PAD_L   8
#define KSPLIT  3
#define KSLICE  3072          // KD / KSPLIT
#define BK      16
#define NT      192           // KSLICE / BK k-tiles per block
#define GEMM_LDS 65536        // 2 dbuf x (Ah,Al,Bh,Bl)[256][16] bf16 -> 2 blocks/CU

typedef unsigned short u16;
typedef __attribute__((ext_vector_type(8)))  __bf16 bf16x8;
typedef __attribute__((ext_vector_type(16))) float  f32x16;

// ---------- fp32 -> (hi,lo) bf16 split, RNE both halves ----------
__device__ __forceinline__ u16 f2bf_rne(float f) {
    unsigned u = __float_as_uint(f);
    u += 0x7FFFu + ((u >> 16) & 1u);
    return (u16)(u >> 16);
}

__device__ __forceinline__ void split4(const float* __restrict__ src,
                                       u16* __restrict__ hi, u16* __restrict__ lo, int i) {
    const float4 v = ((const float4*)src)[i];
    float vv[4] = {v.x, v.y, v.z, v.w};
    u16 hh[4], ll[4];
#pragma unroll
    for (int j = 0; j < 4; ++j) {
        unsigned u = __float_as_uint(vv[j]);
        unsigned r = u + 0x7FFFu + ((u >> 16) & 1u);
        u16 hb = (u16)(r >> 16);
        float hf = __uint_as_float((unsigned)hb << 16);
        hh[j] = hb;
        ll[j] = f2bf_rne(vv[j] - hf);   // residual exact in fp32, then RNE
    }
    ushort4 h, l;
    h.x = hh[0]; h.y = hh[1]; h.z = hh[2]; h.w = hh[3];
    l.x = ll[0]; l.y = ll[1]; l.z = ll[2]; l.w = ll[3];
    ((ushort4*)hi)[i] = h;
    ((ushort4*)lo)[i] = l;
}

// one fused launch: x | w_sin | w_cos regions + zero-init of g
#define NX4  (17694720 / 4)
#define NW4  (23592960 / 4)
#define NG4  (9830400 / 4)
__global__ void split_all_kernel(const float* __restrict__ x,
                                 const float* __restrict__ wss,
                                 const float* __restrict__ wsc,
                                 u16* __restrict__ xh, u16* __restrict__ xl,
                                 u16* __restrict__ wh, u16* __restrict__ wl,
                                 float* __restrict__ g) {
    int i = blockIdx.x * 256 + threadIdx.x;
    if (i < NX4) {
        split4(x, xh, xl, i);
    } else if (i < NX4 + NW4) {
        split4(wss, wh, wl, i - NX4);
    } else if (i < NX4 + 2 * NW4) {
        int j = i - NX4 - NW4;
        split4(wsc, wh + (size_t)NFILT * KD, wl + (size_t)NFILT * KD, j);
    }
    if (i < NG4) {   // fold the g memset into this BW-bound pass
        float4 z; z.x = 0.f; z.y = 0.f; z.z = 0.f; z.w = 0.f;
        ((float4*)g)[i] = z;
    }
}

// ---------- async global->LDS, 16B per lane ----------
__device__ __forceinline__ void glds16(const u16* gp, __bf16* lp) {
    __builtin_amdgcn_global_load_lds(
        (const __attribute__((address_space(1))) void*)gp,
        (__attribute__((address_space(3))) void*)lp, 16, 0, 0);
}

// ---------- bf16x3 split GEMM, 256x256 tile, BK=16, 1 barrier/kt ----------
// C = Ah*Bh + Ah*Bl + Al*Bh   (32x32x16 MFMA, split-K=3, atomic accumulate)
// 64 KB LDS -> 2 blocks/CU: cross-block slip hides the read<->MFMA serialization.
// Swizzle for [256][16] bf16 tiles: 16B granule g of row r stored at g^((r>>2)&1)
// -> each wave64 ds_read_b128 hits every 16B bank-slot class exactly 8x (min cycles).
__global__ __launch_bounds__(512, 4) void gemm_split_kernel(
    const u16* __restrict__ xh, const u16* __restrict__ xl,
    const u16* __restrict__ wh, const u16* __restrict__ wl,
    float* __restrict__ g) {

    extern __shared__ char smem_c[];
    __bf16* const smem = (__bf16*)smem_c;
    // per buffer (16384 elems = 32 KB): Ah +0 | Al +4096 | Bh +8192 | Bl +12288

    const int tid = threadIdx.x;
    const int l   = tid & 63;
    const int w   = tid >> 6;

    // T1: bijective XCD swizzle (480 % 8 == 0)
    int bid = (int)blockIdx.x;
    bid = (bid & 7) * (160 * KSPLIT / 8) + (bid >> 3);
    const int ks = bid / 160;
    const int t  = bid % 160;
    const int m0 = (t / 20) * 256;       // 8 m-tiles (last is half-padded)
    const int n0 = (t % 20) * 256;       // 20 n-tiles
    const unsigned kb = (unsigned)ks * KSLICE;

    // ---- staging: thread -> (row rl, granule gl); linear LDS dest, swizzled src ----
    const int rl  = tid >> 1;                       // 0..255
    const int gl  = tid & 1;
    const int gsw = (gl ^ ((rl >> 2) & 1)) * 8;     // inverse-swizzled source granule
    const int sd  = tid * 8;                        // dest elems = wave base + lane*16B

    int ar = m0 + rl; if (ar > M_DIM - 1) ar = M_DIM - 1;   // clamp pad rows
    const unsigned offA = (unsigned)ar * KD + kb + gsw;
    const unsigned offB = (unsigned)(n0 + rl) * KD + kb + gsw;

#define STAGE(D, KOFF) do {                                          \
        __bf16* sb_ = smem + (D) * 16384;                            \
        glds16(xh + (offA + (KOFF)), sb_ + sd);                      \
        glds16(xl + (offA + (KOFF)), sb_ + 4096  + sd);              \
        glds16(wh + (offB + (KOFF)), sb_ + 8192  + sd);              \
        glds16(wl + (offB + (KOFF)), sb_ + 12288 + sd);              \
    } while (0)

    // ---- compute geometry: 8 waves = 2M x 4N; per-wave C = 128x64 over 2 halves ----
    const int rA = l & 31;
    const int gL = l >> 5;               // k-granule of the fragment (fo = gL*8)
    const int wr = w >> 2;
    const int wc = w & 3;

    int aoff[2][2], boff[2];
#pragma unroll
    for (int h = 0; h < 2; ++h)
#pragma unroll
        for (int mf = 0; mf < 2; ++mf) {
            const int r = h * 128 + wr * 64 + mf * 32 + rA;
            aoff[h][mf] = r * 16 + ((gL ^ ((r >> 2) & 1)) << 3);
        }
#pragma unroll
    for (int nf = 0; nf < 2; ++nf) {
        const int r = wc * 64 + nf * 32 + rA;
        boff[nf] = r * 16 + ((gL ^ ((r >> 2) & 1)) << 3);
    }

    f32x16 acc[4][2];
#pragma unroll
    for (int i = 0; i < 4; ++i)
#pragma unroll
        for (int j = 0; j < 2; ++j)
#pragma unroll
            for (int r = 0; r < 16; ++r)
                acc[i][j][r] = 0.f;

#define MFMA3(ACC, AH, AL, BH, BL)                                              \
    ACC = __builtin_amdgcn_mfma_f32_32x32x16_bf16(AH, BH, ACC, 0, 0, 0);        \
    ACC = __builtin_amdgcn_mfma_f32_32x32x16_bf16(AH, BL, ACC, 0, 0, 0);        \
    ACC = __builtin_amdgcn_mfma_f32_32x32x16_bf16(AL, BH, ACC, 0, 0, 0);

    // ---- prologue: stage k-tile 0 into buf0 ----
    STAGE(0, 0);
    asm volatile("s_waitcnt vmcnt(0)" ::: "memory");
    __builtin_amdgcn_s_barrier();
    __builtin_amdgcn_sched_barrier(0);

    for (int kt = 0; kt < NT; ++kt) {
        const int cur = kt & 1;
        const __bf16* sb = smem + cur * 16384;

        if (kt < NT - 1) STAGE(cur ^ 1, (kt + 1) * BK);   // 4 glds in flight over the kt

        // issue all 12 fragment reads; compiler inserts counted lgkmcnt before uses
        bf16x8 bh_[2], bl_[2], ah_[2][2], al_[2][2];
#pragma unroll
        for (int nf = 0; nf < 2; ++nf) {
            bh_[nf] = *(const bf16x8*)(sb + 8192  + boff[nf]);
            bl_[nf] = *(const bf16x8*)(sb + 12288 + boff[nf]);
        }
#pragma unroll
        for (int h = 0; h < 2; ++h)
#pragma unroll
            for (int mf = 0; mf < 2; ++mf) {
                ah_[h][mf] = *(const bf16x8*)(sb + aoff[h][mf]);
                al_[h][mf] = *(const bf16x8*)(sb + 4096 + aoff[h][mf]);
            }

        __builtin_amdgcn_s_setprio(1);
#pragma unroll
        for (int h = 0; h < 2; ++h)
#pragma unroll
            for (int mf = 0; mf < 2; ++mf)
#pragma unroll
                for (int nf = 0; nf < 2; ++nf) {
                    MFMA3(acc[h * 2 + mf][nf], ah_[h][mf], al_[h][mf], bh_[nf], bl_[nf]);
                }
        __builtin_amdgcn_s_setprio(0);

        asm volatile("s_waitcnt vmcnt(0)" ::: "memory");  // next-kt tiles landed
        __builtin_amdgcn_s_barrier();
        __builtin_amdgcn_sched_barrier(0);
    }

    // ---- epilogue: 32x32 C/D layout col=l&31, row=(r&3)+8*(r>>2)+4*(l>>5) ----
    const int cb = (l >> 5) * 4;
    const int cc = l & 31;
#pragma unroll
    for (int am = 0; am < 4; ++am) {     // am = h*2 + mf
        const int rowb = m0 + (am >> 1) * 128 + wr * 64 + (am & 1) * 32;
        if (rowb < M_DIM) {              // whole 32-row frag in/out (1920%32==0)
#pragma unroll
            for (int nf = 0; nf < 2; ++nf) {
                const int col = n0 + wc * 64 + nf * 32 + cc;
                float* gp = g + (size_t)rowb * N_DIM + col;
#pragma unroll
                for (int r = 0; r < 16; ++r) {
                    const int ro = (r & 3) + 8 * (r >> 2) + cb;
                    atomicAdd(gp + (size_t)ro * N_DIM, acc[am][nf][r]);
                }
            }
        }
    }
#undef STAGE
#undef MFMA3
}

// ---------- depthwise temporal conv + energy, LDS-staged weights ----------
// block = one (b, t, 256-filter chunk); thread = one filter.
__global__ __launch_bounds__(256) void conv_energy_kernel(
    const float* __restrict__ g,
    const float* __restrict__ wts,
    const float* __restrict__ wtc,
    float* __restrict__ out) {

    __shared__ float wl_c[16][256];
    __shared__ float wl_s[16][256];

    const int tid = threadIdx.x;
    const int bid = blockIdx.x;          // 19200 = 8 * 240 * 10
    const int fc  = bid % 10;
    const int t   = (bid / 10) % T_LEN;
    const int b   = bid / (10 * T_LEN);
    const int f0  = fc * 256;

    // cooperative weight load: thread tid owns filter f0+tid's 16 taps
    {
        const float4* wrc = (const float4*)(wtc + (size_t)(f0 + tid) * 16);
        const float4* wrs = (const float4*)(wts + (size_t)(f0 + tid) * 16);
#pragma unroll
        for (int k4 = 0; k4 < 4; ++k4) {
            const float4 vc = wrc[k4];
            const float4 vs = wrs[k4];
            wl_c[k4 * 4 + 0][tid] = vc.x; wl_c[k4 * 4 + 1][tid] = vc.y;
            wl_c[k4 * 4 + 2][tid] = vc.z; wl_c[k4 * 4 + 3][tid] = vc.w;
            wl_s[k4 * 4 + 0][tid] = vs.x; wl_s[k4 * 4 + 1][tid] = vs.y;
            wl_s[k4 * 4 + 2][tid] = vs.z; wl_s[k4 * 4 + 3][tid] = vs.w;
        }
    }
    __syncthreads();

    const float* grow = g + (size_t)b * T_LEN * N_DIM + f0 + tid;
    float s = 0.f, c = 0.f;
#pragma unroll
    for (int j = 0; j < 16; ++j) {
        const int tt = t + j - PAD_L;
        if (tt >= 0 && tt < T_LEN) {     // block-uniform branch (t fixed per block)
            const float gs = grow[(size_t)tt * N_DIM];
            const float gc = grow[(size_t)tt * N_DIM + NFILT];
            const float a  = wl_c[j][tid];
            const float bb = wl_s[j][tid];
            s += gs * a + gc * bb;
            c += gc * a - gs * bb;
        }
    }
    const float r = sqrtf(s * s + c * c);
    out[(size_t)((b * T_LEN + t) * NFILT) + f0 + tid] = logf(r + 1e-5f);
}

extern "C" void kernel_launch(void* const* d_in, const int* in_sizes, int n_in,
                              void* d_out, int out_size, void* d_ws, size_t ws_size,
                              hipStream_t stream) {
    const float* x   = (const float*)d_in[0];  // (8,240,96,96)
    const float* wss = (const float*)d_in[1];  // (2560,96,96)
    const float* wsc = (const float*)d_in[2];  // (2560,96,96)
    const float* wts = (const float*)d_in[3];  // (2560,16)
    const float* wtc = (const float*)d_in[4];  // (2560,16)
    float* out = (float*)d_out;

    // workspace layout (bytes):
    //   xh: 35,389,440 | xl: 35,389,440 | wh: 94,371,840 | wl: 94,371,840 | g: 39,321,600
    char* ws = (char*)d_ws;
    u16*   xh  = (u16*)(ws);
    u16*   xl  = (u16*)(ws + 35389440);
    u16*   whi = (u16*)(ws + 70778880);
    u16*   wlo = (u16*)(ws + 165150720);
    float* g   = (float*)(ws + 259522560);

    static bool gemm_attr_set = false;
    if (!gemm_attr_set) {
        hipFuncSetAttribute(reinterpret_cast<const void*>(gemm_split_kernel),
                            hipFuncAttributeMaxDynamicSharedMemorySize, GEMM_LDS);
        gemm_attr_set = true;
    }

    const int ntot4 = NX4 + 2 * NW4;   // covers NG4 too (NG4 < NX4)
    split_all_kernel<<<(ntot4 + 255) / 256, 256, 0, stream>>>(x, wss, wsc, xh, xl, whi, wlo, g);

    gemm_split_kernel<<<160 * KSPLIT, 512, GEMM_LDS, stream>>>(xh, xl, whi, wlo, g);

    conv_energy_kernel<<<B_SZ * T_LEN * 10, 256, 0, stream>>>(g, wts, wtc, out);
}

// Round 3
// 889.870 us; speedup vs baseline: 11.9907x; 11.9907x over previous
//
#include <hip/hip_runtime.h>

// ---- problem constants ----
#define T_LEN   240
#define B_SZ    8
#define NFILT   2560
#define KD      9216          // 96*96
#define M_DIM   1920          // B*T
#define N_DIM   5120          // 2*NF (sin | cos)
#define PAD_L   8
#define KSPLIT  3
#define KSLICE  3072          // KD / KSPLIT
#define NT      96            // KSLICE / 32 k-tiles per block
#define GEMM_LDS 131072       // 2 dbuf x (Ah,Al,Bh,Bl)[256][32] bf16

typedef unsigned short u16;
typedef __attribute__((ext_vector_type(8)))  __bf16 bf16x8;
typedef __attribute__((ext_vector_type(16))) float  f32x16;

// ---------- fp32 -> (hi,lo) bf16 split, RNE both halves ----------
__device__ __forceinline__ u16 f2bf_rne(float f) {
    unsigned u = __float_as_uint(f);
    u += 0x7FFFu + ((u >> 16) & 1u);
    return (u16)(u >> 16);
}

__device__ __forceinline__ void split4(const float* __restrict__ src,
                                       u16* __restrict__ hi, u16* __restrict__ lo, int i) {
    const float4 v = ((const float4*)src)[i];
    float vv[4] = {v.x, v.y, v.z, v.w};
    u16 hh[4], ll[4];
#pragma unroll
    for (int j = 0; j < 4; ++j) {
        unsigned u = __float_as_uint(vv[j]);
        unsigned r = u + 0x7FFFu + ((u >> 16) & 1u);
        u16 hb = (u16)(r >> 16);
        float hf = __uint_as_float((unsigned)hb << 16);
        hh[j] = hb;
        ll[j] = f2bf_rne(vv[j] - hf);   // residual exact in fp32, then RNE
    }
    ushort4 h, l;
    h.x = hh[0]; h.y = hh[1]; h.z = hh[2]; h.w = hh[3];
    l.x = ll[0]; l.y = ll[1]; l.z = ll[2]; l.w = ll[3];
    ((ushort4*)hi)[i] = h;
    ((ushort4*)lo)[i] = l;
}

// one fused launch: x | w_sin | w_cos regions + zero-init of g
#define NX4  (17694720 / 4)
#define NW4  (23592960 / 4)
#define NG4  (9830400 / 4)
__global__ void split_all_kernel(const float* __restrict__ x,
                                 const float* __restrict__ wss,
                                 const float* __restrict__ wsc,
                                 u16* __restrict__ xh, u16* __restrict__ xl,
                                 u16* __restrict__ wh, u16* __restrict__ wl,
                                 float* __restrict__ g) {
    int i = blockIdx.x * 256 + threadIdx.x;
    if (i < NX4) {
        split4(x, xh, xl, i);
    } else if (i < NX4 + NW4) {
        split4(wss, wh, wl, i - NX4);
    } else if (i < NX4 + 2 * NW4) {
        int j = i - NX4 - NW4;
        split4(wsc, wh + (size_t)NFILT * KD, wl + (size_t)NFILT * KD, j);
    }
    if (i < NG4) {   // fold the g memset into this BW-bound pass
        float4 z; z.x = 0.f; z.y = 0.f; z.z = 0.f; z.w = 0.f;
        ((float4*)g)[i] = z;
    }
}

// ---------- async global->LDS, 16B per lane ----------
__device__ __forceinline__ void glds16(const u16* gp, __bf16* lp) {
    __builtin_amdgcn_global_load_lds(
        (const __attribute__((address_space(1))) void*)gp,
        (__attribute__((address_space(3))) void*)lp, 16, 0, 0);
}

// swizzled element offset within a [256][32] bf16 tile.
// 16B granule g of row r is XOR'd with (r>>1)&3 -> a wave's 64-lane
// ds_read_b128 spreads across all 32 banks at the 8-access minimum.
__device__ __forceinline__ int frag_off(int r, int fo) {
    return r * 32 + (((fo >> 3) ^ ((r >> 1) & 3)) << 3);
}

// ---------- bf16x3 split GEMM, 256x256 tile, BK=32, 4-phase/kt pipeline ----
// C = Ah*Bh + Ah*Bl + Al*Bh   (32x32x16 MFMA, split-K=3, atomic accumulate)
// m201-style schedule: per phase {ds_read frags | 2 glds units | barrier |
// lgkmcnt(0) | 12 MFMA (setprio) | counted vmcnt | barrier}. vmcnt never
// drains to 0 mid-loop: staging units span barriers, DS overlaps MFMA.
__global__ __launch_bounds__(512, 2) void gemm_split_kernel(
    const u16* __restrict__ xh, const u16* __restrict__ xl,
    const u16* __restrict__ wh, const u16* __restrict__ wl,
    float* __restrict__ g) {

    extern __shared__ char smem_c[];
    __bf16* const smem = (__bf16*)smem_c;
    // per dbuf (32768 elems): Ah +0 (h0 0..4096, h1 4096..8192) | Al +8192
    //                         Bh +16384 | Bl +24576

    const int tid = threadIdx.x;
    const int l   = tid & 63;
    const int w   = tid >> 6;

    // T1: bijective XCD swizzle (480 % 8 == 0)
    int bid = (int)blockIdx.x;
    bid = (bid & 7) * (160 * KSPLIT / 8) + (bid >> 3);
    const int ks = bid / 160;
    const int t  = bid % 160;
    const int m0 = (t / 20) * 256;       // 8 m-tiles (last is half-padded)
    const int n0 = (t % 20) * 256;       // 20 n-tiles
    const unsigned kb = (unsigned)ks * KSLICE;

    // ---- staging geometry: lane-linear LDS dest, inverse-swizzled source ----
    const int rl  = w * 16 + (l >> 2);                     // row in 128-row half
    const int gsw = ((l & 3) ^ ((rl >> 1) & 3)) * 8;       // swizzled src granule
    const int sd  = w * 512 + l * 8;                       // dest = base + lane*16B

    int ar0 = m0 + rl;        if (ar0 > M_DIM - 1) ar0 = M_DIM - 1;  // clamp pad
    int ar1 = m0 + rl + 128;  if (ar1 > M_DIM - 1) ar1 = M_DIM - 1;
    const unsigned offA0 = (unsigned)ar0 * KD + kb + gsw;
    const unsigned offA1 = (unsigned)ar1 * KD + kb + gsw;
    const unsigned offB0 = (unsigned)(n0 + rl) * KD + kb + gsw;
    const unsigned offB1 = (unsigned)(n0 + rl + 128) * KD + kb + gsw;

    // stage units, issued 2/phase in fixed order: Bh | Bl | A-h0 | A-h1
#define ST_BH(D,KO) do { __bf16* s_ = smem + (D)*32768;                 \
        glds16(wh + (offB0 + (KO)), s_ + 16384 + sd);                   \
        glds16(wh + (offB1 + (KO)), s_ + 20480 + sd); } while (0)
#define ST_BL(D,KO) do { __bf16* s_ = smem + (D)*32768;                 \
        glds16(wl + (offB0 + (KO)), s_ + 24576 + sd);                   \
        glds16(wl + (offB1 + (KO)), s_ + 28672 + sd); } while (0)
#define ST_A0(D,KO) do { __bf16* s_ = smem + (D)*32768;                 \
        glds16(xh + (offA0 + (KO)), s_ + 0     + sd);                   \
        glds16(xl + (offA0 + (KO)), s_ + 8192  + sd); } while (0)
#define ST_A1(D,KO) do { __bf16* s_ = smem + (D)*32768;                 \
        glds16(xh + (offA1 + (KO)), s_ + 4096  + sd);                   \
        glds16(xl + (offA1 + (KO)), s_ + 12288 + sd); } while (0)

    // ---- compute geometry: 8 waves = 2M x 4N; per-wave C = 128x64 ----
    const int rA = l & 31;
    const int kq = (l >> 5) * 8;
    const int wr = w >> 2;
    const int wc = w & 3;

    int aoff[2][2][2], boff[2][2];       // [h][mf][s] / [nf][s]
#pragma unroll
    for (int h = 0; h < 2; ++h)
#pragma unroll
        for (int mf = 0; mf < 2; ++mf)
#pragma unroll
            for (int s = 0; s < 2; ++s)
                aoff[h][mf][s] = frag_off(h * 128 + wr * 64 + mf * 32 + rA, s * 16 + kq);
#pragma unroll
    for (int nf = 0; nf < 2; ++nf)
#pragma unroll
        for (int s = 0; s < 2; ++s)
            boff[nf][s] = frag_off(wc * 64 + nf * 32 + rA, s * 16 + kq);

    f32x16 acc[4][2];
#pragma unroll
    for (int i = 0; i < 4; ++i)
#pragma unroll
        for (int j = 0; j < 2; ++j)
#pragma unroll
            for (int r = 0; r < 16; ++r)
                acc[i][j][r] = 0.f;

#define MFMA3(ACC, AH, AL, BH, BL)                                              \
    ACC = __builtin_amdgcn_mfma_f32_32x32x16_bf16(AH, BH, ACC, 0, 0, 0);        \
    ACC = __builtin_amdgcn_mfma_f32_32x32x16_bf16(AH, BL, ACC, 0, 0, 0);        \
    ACC = __builtin_amdgcn_mfma_f32_32x32x16_bf16(AL, BH, ACC, 0, 0, 0);

#define MFMA_CLUSTER(H, S) do {                                                 \
        __builtin_amdgcn_s_setprio(1);                                          \
        MFMA3(acc[(H)*2 + 0][0], ah_[0], al_[0], bh_[0][S], bl_[0][S]);         \
        MFMA3(acc[(H)*2 + 0][1], ah_[0], al_[0], bh_[1][S], bl_[1][S]);         \
        MFMA3(acc[(H)*2 + 1][0], ah_[1], al_[1], bh_[0][S], bl_[0][S]);         \
        MFMA3(acc[(H)*2 + 1][1], ah_[1], al_[1], bh_[1][S], bl_[1][S]);         \
        __builtin_amdgcn_s_setprio(0);                                          \
    } while (0)

#define LOAD_A(H, S) do {                                                       \
        ah_[0] = *(const bf16x8*)(sb + aoff[H][0][S]);                          \
        ah_[1] = *(const bf16x8*)(sb + aoff[H][1][S]);                          \
        al_[0] = *(const bf16x8*)(sb + 8192 + aoff[H][0][S]);                   \
        al_[1] = *(const bf16x8*)(sb + 8192 + aoff[H][1][S]);                   \
    } while (0)

#define SYNC_IN() do {                                                          \
        __builtin_amdgcn_s_barrier();                                           \
        asm volatile("s_waitcnt lgkmcnt(0)" ::: "memory");                      \
        __builtin_amdgcn_sched_barrier(0);                                      \
    } while (0)

    // ---- prologue: stage k-tile 0 (order: Bh,Bl,A0,A1), leave A1 in flight ----
    ST_BH(0, 0); ST_BL(0, 0); ST_A0(0, 0); ST_A1(0, 0);
    asm volatile("s_waitcnt vmcnt(2)" ::: "memory");
    __builtin_amdgcn_s_barrier();

    for (int kt = 0; kt < NT; ++kt) {
        const int cur = kt & 1;
        const int nxt = cur ^ 1;
        const __bf16* sb = smem + cur * 32768;
        const int ko = (kt + 1) * 32;
        const bool pf = (kt < NT - 1);

        bf16x8 bh_[2][2], bl_[2][2], ah_[2], al_[2];

        // ---- phase 1: (h0, s0); stage Bh(kt+1) ----
#pragma unroll
        for (int nf = 0; nf < 2; ++nf)
#pragma unroll
            for (int s = 0; s < 2; ++s) {
                bh_[nf][s] = *(const bf16x8*)(sb + 16384 + boff[nf][s]);
                bl_[nf][s] = *(const bf16x8*)(sb + 24576 + boff[nf][s]);
            }
        LOAD_A(0, 0);
        if (pf) ST_BH(nxt, ko);
        SYNC_IN();
        MFMA_CLUSTER(0, 0);
        __builtin_amdgcn_s_barrier();

        // ---- phase 2: (h0, s1); stage Bl(kt+1); wait A-h1(kt) landed ----
        LOAD_A(0, 1);
        if (pf) ST_BL(nxt, ko);
        SYNC_IN();
        MFMA_CLUSTER(0, 1);
        if (pf) { asm volatile("s_waitcnt vmcnt(4)" ::: "memory"); }
        else    { asm volatile("s_waitcnt vmcnt(0)" ::: "memory"); }
        __builtin_amdgcn_s_barrier();

        // ---- phase 3: (h1, s0); stage A-h0(kt+1) ----
        LOAD_A(1, 0);
        if (pf) ST_A0(nxt, ko);
        SYNC_IN();
        MFMA_CLUSTER(1, 0);
        __builtin_amdgcn_s_barrier();

        // ---- phase 4: (h1, s1); stage A-h1(kt+1); wait Bh,Bl,A-h0(kt+1) ----
        LOAD_A(1, 1);
        if (pf) ST_A1(nxt, ko);
        SYNC_IN();
        MFMA_CLUSTER(1, 1);
        if (pf) { asm volatile("s_waitcnt vmcnt(2)" ::: "memory"); }
        __builtin_amdgcn_s_barrier();
    }

    // ---- epilogue: 32x32 C/D layout col=l&31, row=(r&3)+8*(r>>2)+4*(l>>5) ----
    const int cb = (l >> 5) * 4;
    const int cc = l & 31;
#pragma unroll
    for (int am = 0; am < 4; ++am) {     // am = h*2 + mf
        const int rowb = m0 + (am >> 1) * 128 + wr * 64 + (am & 1) * 32;
        if (rowb < M_DIM) {              // whole 32-row frag in/out (1920%32==0)
#pragma unroll
            for (int nf = 0; nf < 2; ++nf) {
                const int col = n0 + wc * 64 + nf * 32 + cc;
                float* gp = g + (size_t)rowb * N_DIM + col;
#pragma unroll
                for (int r = 0; r < 16; ++r) {
                    const int ro = (r & 3) + 8 * (r >> 2) + cb;
                    atomicAdd(gp + (size_t)ro * N_DIM, acc[am][nf][r]);
                }
            }
        }
    }
#undef ST_BH
#undef ST_BL
#undef ST_A0
#undef ST_A1
#undef MFMA3
#undef MFMA_CLUSTER
#undef LOAD_A
#undef SYNC_IN
}

// ---------- depthwise temporal conv + energy, LDS-staged weights ----------
// block = one (b, t, 256-filter chunk); thread = one filter.
__global__ __launch_bounds__(256) void conv_energy_kernel(
    const float* __restrict__ g,
    const float* __restrict__ wts,
    const float* __restrict__ wtc,
    float* __restrict__ out) {

    __shared__ float wl_c[16][256];
    __shared__ float wl_s[16][256];

    const int tid = threadIdx.x;
    const int bid = blockIdx.x;          // 19200 = 8 * 240 * 10
    const int fc  = bid % 10;
    const int t   = (bid / 10) % T_LEN;
    const int b   = bid / (10 * T_LEN);
    const int f0  = fc * 256;

    // cooperative weight load: thread tid owns filter f0+tid's 16 taps
    {
        const float4* wrc = (const float4*)(wtc + (size_t)(f0 + tid) * 16);
        const float4* wrs = (const float4*)(wts + (size_t)(f0 + tid) * 16);
#pragma unroll
        for (int k4 = 0; k4 < 4; ++k4) {
            const float4 vc = wrc[k4];
            const float4 vs = wrs[k4];
            wl_c[k4 * 4 + 0][tid] = vc.x; wl_c[k4 * 4 + 1][tid] = vc.y;
            wl_c[k4 * 4 + 2][tid] = vc.z; wl_c[k4 * 4 + 3][tid] = vc.w;
            wl_s[k4 * 4 + 0][tid] = vs.x; wl_s[k4 * 4 + 1][tid] = vs.y;
            wl_s[k4 * 4 + 2][tid] = vs.z; wl_s[k4 * 4 + 3][tid] = vs.w;
        }
    }
    __syncthreads();

    const float* grow = g + (size_t)b * T_LEN * N_DIM + f0 + tid;
    float s = 0.f, c = 0.f;
#pragma unroll
    for (int j = 0; j < 16; ++j) {
        const int tt = t + j - PAD_L;
        if (tt >= 0 && tt < T_LEN) {     // block-uniform branch (t fixed per block)
            const float gs = grow[(size_t)tt * N_DIM];
            const float gc = grow[(size_t)tt * N_DIM + NFILT];
            const float a  = wl_c[j][tid];
            const float bb = wl_s[j][tid];
            s += gs * a + gc * bb;
            c += gc * a - gs * bb;
        }
    }
    const float r = sqrtf(s * s + c * c);
    out[(size_t)((b * T_LEN + t) * NFILT) + f0 + tid] = logf(r + 1e-5f);
}

extern "C" void kernel_launch(void* const* d_in, const int* in_sizes, int n_in,
                              void* d_out, int out_size, void* d_ws, size_t ws_size,
                              hipStream_t stream) {
    const float* x   = (const float*)d_in[0];  // (8,240,96,96)
    const float* wss = (const float*)d_in[1];  // (2560,96,96)
    const float* wsc = (const float*)d_in[2];  // (2560,96,96)
    const float* wts = (const float*)d_in[3];  // (2560,16)
    const float* wtc = (const float*)d_in[4];  // (2560,16)
    float* out = (float*)d_out;

    // workspace layout (bytes):
    //   xh: 35,389,440 | xl: 35,389,440 | wh: 94,371,840 | wl: 94,371,840 | g: 39,321,600
    char* ws = (char*)d_ws;
    u16*   xh  = (u16*)(ws);
    u16*   xl  = (u16*)(ws + 35389440);
    u16*   whi = (u16*)(ws + 70778880);
    u16*   wlo = (u16*)(ws + 165150720);
    float* g   = (float*)(ws + 259522560);

    static bool gemm_attr_set = false;
    if (!gemm_attr_set) {
        hipFuncSetAttribute(reinterpret_cast<const void*>(gemm_split_kernel),
                            hipFuncAttributeMaxDynamicSharedMemorySize, GEMM_LDS);
        gemm_attr_set = true;
    }

    const int ntot4 = NX4 + 2 * NW4;   // covers NG4 too (NG4 < NX4)
    split_all_kernel<<<(ntot4 + 255) / 256, 256, 0, stream>>>(x, wss, wsc, xh, xl, whi, wlo, g);

    gemm_split_kernel<<<160 * KSPLIT, 512, GEMM_LDS, stream>>>(xh, xl, whi, wlo, g);

    conv_energy_kernel<<<B_SZ * T_LEN * 10, 256, 0, stream>>>(g, wts, wtc, out);
}

// Round 4
// 879.800 us; speedup vs baseline: 12.1280x; 1.0114x over previous
//
#include <hip/hip_runtime.h>

// ---- problem constants ----
#define T_LEN   240
#define B_SZ    8
#define NFILT   2560
#define KD      9216          // 96*96
#define M_DIM   1920          // B*T
#define N_DIM   5120          // 2*NF (sin | cos)
#define PAD_L   8
#define KSPLIT  3
#define KSLICE  3072          // KD / KSPLIT
#define NT      96            // KSLICE / 32 k-tiles per block
#define GEMM_LDS 131072       // 2 dbuf x (Ah,Al,Bh,Bl)[256][32] bf16

typedef unsigned short u16;
typedef __attribute__((ext_vector_type(8)))  __bf16 bf16x8;
typedef __attribute__((ext_vector_type(16))) float  f32x16;

// ---------- fp32 -> (hi,lo) bf16 split, RNE both halves ----------
__device__ __forceinline__ u16 f2bf_rne(float f) {
    unsigned u = __float_as_uint(f);
    u += 0x7FFFu + ((u >> 16) & 1u);
    return (u16)(u >> 16);
}

__device__ __forceinline__ void split4(const float* __restrict__ src,
                                       u16* __restrict__ hi, u16* __restrict__ lo, int i) {
    const float4 v = ((const float4*)src)[i];
    float vv[4] = {v.x, v.y, v.z, v.w};
    u16 hh[4], ll[4];
#pragma unroll
    for (int j = 0; j < 4; ++j) {
        unsigned u = __float_as_uint(vv[j]);
        unsigned r = u + 0x7FFFu + ((u >> 16) & 1u);
        u16 hb = (u16)(r >> 16);
        float hf = __uint_as_float((unsigned)hb << 16);
        hh[j] = hb;
        ll[j] = f2bf_rne(vv[j] - hf);   // residual exact in fp32, then RNE
    }
    ushort4 h, l;
    h.x = hh[0]; h.y = hh[1]; h.z = hh[2]; h.w = hh[3];
    l.x = ll[0]; l.y = ll[1]; l.z = ll[2]; l.w = ll[3];
    ((ushort4*)hi)[i] = h;
    ((ushort4*)lo)[i] = l;
}

// one fused launch: x | w_sin | w_cos regions + zero-init of g
#define NX4  (17694720 / 4)
#define NW4  (23592960 / 4)
#define NG4  (9830400 / 4)
__global__ void split_all_kernel(const float* __restrict__ x,
                                 const float* __restrict__ wss,
                                 const float* __restrict__ wsc,
                                 u16* __restrict__ xh, u16* __restrict__ xl,
                                 u16* __restrict__ wh, u16* __restrict__ wl,
                                 float* __restrict__ g) {
    int i = blockIdx.x * 256 + threadIdx.x;
    if (i < NX4) {
        split4(x, xh, xl, i);
    } else if (i < NX4 + NW4) {
        split4(wss, wh, wl, i - NX4);
    } else if (i < NX4 + 2 * NW4) {
        int j = i - NX4 - NW4;
        split4(wsc, wh + (size_t)NFILT * KD, wl + (size_t)NFILT * KD, j);
    }
    if (i < NG4) {   // fold the g memset into this BW-bound pass
        float4 z; z.x = 0.f; z.y = 0.f; z.z = 0.f; z.w = 0.f;
        ((float4*)g)[i] = z;
    }
}

// ---------- async global->LDS, 16B per lane ----------
__device__ __forceinline__ void glds16(const u16* gp, __bf16* lp) {
    __builtin_amdgcn_global_load_lds(
        (const __attribute__((address_space(1))) void*)gp,
        (__attribute__((address_space(3))) void*)lp, 16, 0, 0);
}

// swizzled element offset within a [256][32] bf16 tile.
// 16B granule g of row r is XOR'd with (r>>1)&3 -> a wave's 64-lane
// ds_read_b128 spreads across all 32 banks at the 8-access minimum.
__device__ __forceinline__ int frag_off(int r, int fo) {
    return r * 32 + (((fo >> 3) ^ ((r >> 1) & 3)) << 3);
}

// ---------- bf16x3 split GEMM, 256x256 tile, BK=32, 2-region/kt pipeline ----
// C = Ah*Bh + Ah*Bl + Al*Bh   (32x32x16 MFMA, split-K=3, atomic accumulate)
// 2 barriers/kt (minimum for dbuf + counted-vmcnt choreography). NO manual
// lgkmcnt fences: compiler emits counted lgkmcnt per MFMA so the LDS read
// drain (2304 cyc/kt/CU) overlaps the MFMA stream (3100 cyc/kt/CU).
// vmcnt never drains to 0 mid-loop: A1(kt+1) stays in flight across kt end.
__global__ __launch_bounds__(512, 2) void gemm_split_kernel(
    const u16* __restrict__ xh, const u16* __restrict__ xl,
    const u16* __restrict__ wh, const u16* __restrict__ wl,
    float* __restrict__ g) {

    extern __shared__ char smem_c[];
    __bf16* const smem = (__bf16*)smem_c;
    // per dbuf (32768 elems): Ah +0 (h0 0..4096, h1 4096..8192) | Al +8192
    //                         Bh +16384 | Bl +24576

    const int tid = threadIdx.x;
    const int l   = tid & 63;
    const int w   = tid >> 6;

    // T1: bijective XCD swizzle (480 % 8 == 0)
    int bid = (int)blockIdx.x;
    bid = (bid & 7) * (160 * KSPLIT / 8) + (bid >> 3);
    const int ks = bid / 160;
    const int t  = bid % 160;
    const int m0 = (t / 20) * 256;       // 8 m-tiles (last is half-padded)
    const int n0 = (t % 20) * 256;       // 20 n-tiles
    const unsigned kb = (unsigned)ks * KSLICE;
    const bool mhalf = (m0 + 128 >= M_DIM);   // last m-tile: h1 rows all OOB

    // ---- staging geometry: lane-linear LDS dest, inverse-swizzled source ----
    const int rl  = w * 16 + (l >> 2);                     // row in 128-row half
    const int gsw = ((l & 3) ^ ((rl >> 1) & 3)) * 8;       // swizzled src granule
    const int sd  = w * 512 + l * 8;                       // dest = base + lane*16B

    int ar0 = m0 + rl;        if (ar0 > M_DIM - 1) ar0 = M_DIM - 1;  // clamp pad
    int ar1 = m0 + rl + 128;  if (ar1 > M_DIM - 1) ar1 = M_DIM - 1;
    const unsigned offA0 = (unsigned)ar0 * KD + kb + gsw;
    const unsigned offA1 = (unsigned)ar1 * KD + kb + gsw;
    const unsigned offB0 = (unsigned)(n0 + rl) * KD + kb + gsw;
    const unsigned offB1 = (unsigned)(n0 + rl + 128) * KD + kb + gsw;

    // stage units (2 glds16/thread each); issue order: Bh | Bl | A-h0 | A-h1
#define ST_BH(D,KO) do { __bf16* s_ = smem + (D)*32768;                 \
        glds16(wh + (offB0 + (KO)), s_ + 16384 + sd);                   \
        glds16(wh + (offB1 + (KO)), s_ + 20480 + sd); } while (0)
#define ST_BL(D,KO) do { __bf16* s_ = smem + (D)*32768;                 \
        glds16(wl + (offB0 + (KO)), s_ + 24576 + sd);                   \
        glds16(wl + (offB1 + (KO)), s_ + 28672 + sd); } while (0)
#define ST_A0(D,KO) do { __bf16* s_ = smem + (D)*32768;                 \
        glds16(xh + (offA0 + (KO)), s_ + 0     + sd);                   \
        glds16(xl + (offA0 + (KO)), s_ + 8192  + sd); } while (0)
#define ST_A1(D,KO) do { __bf16* s_ = smem + (D)*32768;                 \
        glds16(xh + (offA1 + (KO)), s_ + 4096  + sd);                   \
        glds16(xl + (offA1 + (KO)), s_ + 12288 + sd); } while (0)

    // ---- compute geometry: 8 waves = 2M x 4N; per-wave C = 128x64 ----
    const int rA = l & 31;
    const int kq = (l >> 5) * 8;
    const int wr = w >> 2;
    const int wc = w & 3;

    int aoff[2][2][2], boff[2][2];       // [h][mf][s] / [nf][s]
#pragma unroll
    for (int h = 0; h < 2; ++h)
#pragma unroll
        for (int mf = 0; mf < 2; ++mf)
#pragma unroll
            for (int s = 0; s < 2; ++s)
                aoff[h][mf][s] = frag_off(h * 128 + wr * 64 + mf * 32 + rA, s * 16 + kq);
#pragma unroll
    for (int nf = 0; nf < 2; ++nf)
#pragma unroll
        for (int s = 0; s < 2; ++s)
            boff[nf][s] = frag_off(wc * 64 + nf * 32 + rA, s * 16 + kq);

    f32x16 acc[4][2];
#pragma unroll
    for (int i = 0; i < 4; ++i)
#pragma unroll
        for (int j = 0; j < 2; ++j)
#pragma unroll
            for (int r = 0; r < 16; ++r)
                acc[i][j][r] = 0.f;

#define MFMA3(ACC, AH, AL, BH, BL)                                              \
    ACC = __builtin_amdgcn_mfma_f32_32x32x16_bf16(AH, BH, ACC, 0, 0, 0);        \
    ACC = __builtin_amdgcn_mfma_f32_32x32x16_bf16(AH, BL, ACC, 0, 0, 0);        \
    ACC = __builtin_amdgcn_mfma_f32_32x32x16_bf16(AL, BH, ACC, 0, 0, 0);

    // ---- prologue: stage k-tile 0 (Bh,Bl,A0,A1); leave A1 in flight ----
    ST_BH(0, 0); ST_BL(0, 0); ST_A0(0, 0); ST_A1(0, 0);
    asm volatile("s_waitcnt vmcnt(2)" ::: "memory");
    __builtin_amdgcn_s_barrier();

    for (int kt = 0; kt < NT; ++kt) {
        const int cur = kt & 1;
        const int nxt = cur ^ 1;
        const __bf16* sb = smem + cur * 32768;
        const int ko = (kt + 1) * 32;
        const bool pf = (kt < NT - 1);

        bf16x8 bh_[2][2], bl_[2][2], ah_[2][2], al_[2][2];

        // ================= region 1: h0 rows; stage Bh,Bl(kt+1) =================
        if (pf) { ST_BH(nxt, ko); ST_BL(nxt, ko); }
        // reads in consumption order: s0 group first -> first MFMA unblocks early
#pragma unroll
        for (int s = 0; s < 2; ++s) {
#pragma unroll
            for (int nf = 0; nf < 2; ++nf) {
                bh_[nf][s] = *(const bf16x8*)(sb + 16384 + boff[nf][s]);
                bl_[nf][s] = *(const bf16x8*)(sb + 24576 + boff[nf][s]);
            }
#pragma unroll
            for (int mf = 0; mf < 2; ++mf) {
                ah_[mf][s] = *(const bf16x8*)(sb + aoff[0][mf][s]);
                al_[mf][s] = *(const bf16x8*)(sb + 8192 + aoff[0][mf][s]);
            }
        }
        __builtin_amdgcn_s_setprio(1);
#pragma unroll
        for (int s = 0; s < 2; ++s)
#pragma unroll
            for (int mf = 0; mf < 2; ++mf)
#pragma unroll
                for (int nf = 0; nf < 2; ++nf) {
                    MFMA3(acc[mf][nf], ah_[mf][s], al_[mf][s], bh_[nf][s], bl_[nf][s]);
                }
        __builtin_amdgcn_s_setprio(0);
        if (pf) { asm volatile("s_waitcnt vmcnt(4)" ::: "memory"); }  // A1(cur) landed
        else    { asm volatile("s_waitcnt vmcnt(0)" ::: "memory"); }
        __builtin_amdgcn_s_barrier();

        // ================= region 2: h1 rows; stage A0,A1(kt+1) =================
        if (pf) { ST_A0(nxt, ko); ST_A1(nxt, ko); }
        if (!mhalf) {
#pragma unroll
            for (int s = 0; s < 2; ++s)
#pragma unroll
                for (int mf = 0; mf < 2; ++mf) {
                    ah_[mf][s] = *(const bf16x8*)(sb + aoff[1][mf][s]);
                    al_[mf][s] = *(const bf16x8*)(sb + 8192 + aoff[1][mf][s]);
                }
            __builtin_amdgcn_s_setprio(1);
#pragma unroll
            for (int s = 0; s < 2; ++s)
#pragma unroll
                for (int mf = 0; mf < 2; ++mf)
#pragma unroll
                    for (int nf = 0; nf < 2; ++nf) {
                        MFMA3(acc[2 + mf][nf], ah_[mf][s], al_[mf][s], bh_[nf][s], bl_[nf][s]);
                    }
            __builtin_amdgcn_s_setprio(0);
        }
        if (pf) { asm volatile("s_waitcnt vmcnt(2)" ::: "memory"); }  // Bh,Bl,A0(kt+1) landed
        __builtin_amdgcn_s_barrier();
    }

    // ---- epilogue: 32x32 C/D layout col=l&31, row=(r&3)+8*(r>>2)+4*(l>>5) ----
    const int cb = (l >> 5) * 4;
    const int cc = l & 31;
#pragma unroll
    for (int am = 0; am < 4; ++am) {     // am = h*2 + mf
        const int rowb = m0 + (am >> 1) * 128 + wr * 64 + (am & 1) * 32;
        if (rowb < M_DIM) {              // whole 32-row frag in/out (1920%32==0)
#pragma unroll
            for (int nf = 0; nf < 2; ++nf) {
                const int col = n0 + wc * 64 + nf * 32 + cc;
                float* gp = g + (size_t)rowb * N_DIM + col;
#pragma unroll
                for (int r = 0; r < 16; ++r) {
                    const int ro = (r & 3) + 8 * (r >> 2) + cb;
                    atomicAdd(gp + (size_t)ro * N_DIM, acc[am][nf][r]);
                }
            }
        }
    }
#undef ST_BH
#undef ST_BL
#undef ST_A0
#undef ST_A1
#undef MFMA3
}

// ---------- depthwise temporal conv + energy, LDS-staged weights ----------
// block = one (b, t, 256-filter chunk); thread = one filter.
__global__ __launch_bounds__(256) void conv_energy_kernel(
    const float* __restrict__ g,
    const float* __restrict__ wts,
    const float* __restrict__ wtc,
    float* __restrict__ out) {

    __shared__ float wl_c[16][256];
    __shared__ float wl_s[16][256];

    const int tid = threadIdx.x;
    const int bid = blockIdx.x;          // 19200 = 8 * 240 * 10
    const int fc  = bid % 10;
    const int t   = (bid / 10) % T_LEN;
    const int b   = bid / (10 * T_LEN);
    const int f0  = fc * 256;

    // cooperative weight load: thread tid owns filter f0+tid's 16 taps
    {
        const float4* wrc = (const float4*)(wtc + (size_t)(f0 + tid) * 16);
        const float4* wrs = (const float4*)(wts + (size_t)(f0 + tid) * 16);
#pragma unroll
        for (int k4 = 0; k4 < 4; ++k4) {
            const float4 vc = wrc[k4];
            const float4 vs = wrs[k4];
            wl_c[k4 * 4 + 0][tid] = vc.x; wl_c[k4 * 4 + 1][tid] = vc.y;
            wl_c[k4 * 4 + 2][tid] = vc.z; wl_c[k4 * 4 + 3][tid] = vc.w;
            wl_s[k4 * 4 + 0][tid] = vs.x; wl_s[k4 * 4 + 1][tid] = vs.y;
            wl_s[k4 * 4 + 2][tid] = vs.z; wl_s[k4 * 4 + 3][tid] = vs.w;
        }
    }
    __syncthreads();

    const float* grow = g + (size_t)b * T_LEN * N_DIM + f0 + tid;
    float s = 0.f, c = 0.f;
#pragma unroll
    for (int j = 0; j < 16; ++j) {
        const int tt = t + j - PAD_L;
        if (tt >= 0 && tt < T_LEN) {     // block-uniform branch (t fixed per block)
            const float gs = grow[(size_t)tt * N_DIM];
            const float gc = grow[(size_t)tt * N_DIM + NFILT];
            const float a  = wl_c[j][tid];
            const float bb = wl_s[j][tid];
            s += gs * a + gc * bb;
            c += gc * a - gs * bb;
        }
    }
    const float r = sqrtf(s * s + c * c);
    out[(size_t)((b * T_LEN + t) * NFILT) + f0 + tid] = logf(r + 1e-5f);
}

extern "C" void kernel_launch(void* const* d_in, const int* in_sizes, int n_in,
                              void* d_out, int out_size, void* d_ws, size_t ws_size,
                              hipStream_t stream) {
    const float* x   = (const float*)d_in[0];  // (8,240,96,96)
    const float* wss = (const float*)d_in[1];  // (2560,96,96)
    const float* wsc = (const float*)d_in[2];  // (2560,96,96)
    const float* wts = (const float*)d_in[3];  // (2560,16)
    const float* wtc = (const float*)d_in[4];  // (2560,16)
    float* out = (float*)d_out;

    // workspace layout (bytes):
    //   xh: 35,389,440 | xl: 35,389,440 | wh: 94,371,840 | wl: 94,371,840 | g: 39,321,600
    char* ws = (char*)d_ws;
    u16*   xh  = (u16*)(ws);
    u16*   xl  = (u16*)(ws + 35389440);
    u16*   whi = (u16*)(ws + 70778880);
    u16*   wlo = (u16*)(ws + 165150720);
    float* g   = (float*)(ws + 259522560);

    static bool gemm_attr_set = false;
    if (!gemm_attr_set) {
        hipFuncSetAttribute(reinterpret_cast<const void*>(gemm_split_kernel),
                            hipFuncAttributeMaxDynamicSharedMemorySize, GEMM_LDS);
        gemm_attr_set = true;
    }

    const int ntot4 = NX4 + 2 * NW4;   // covers NG4 too (NG4 < NX4)
    split_all_kernel<<<(ntot4 + 255) / 256, 256, 0, stream>>>(x, wss, wsc, xh, xl, whi, wlo, g);

    gemm_split_kernel<<<160 * KSPLIT, 512, GEMM_LDS, stream>>>(xh, xl, whi, wlo, g);

    conv_energy_kernel<<<B_SZ * T_LEN * 10, 256, 0, stream>>>(g, wts, wtc, out);
}

// Round 6
// 778.091 us; speedup vs baseline: 13.7133x; 1.1307x over previous
//
#include <hip/hip_runtime.h>

// ---- problem constants ----
#define T_LEN   240
#define B_SZ    8
#define NFILT   2560
#define KD      9216          // 96*96
#define M_DIM   1920          // B*T
#define N_DIM   5120          // 2*NF (sin | cos)
#define PAD_L   8
#define KSPLIT  3
#define KSLICE  3072          // KD / KSPLIT
#define NT      96            // KSLICE / 32 k-tiles per block
#define GEMM_LDS 131072       // 2 dbuf x (Ah,Al,Bh,Bl)[256][32] bf16

typedef unsigned short u16;
typedef __attribute__((ext_vector_type(8)))  __bf16 bf16x8;
typedef __attribute__((ext_vector_type(16))) float  f32x16;

// ---------- fp32 -> (hi,lo) bf16 split, RNE both halves ----------
__device__ __forceinline__ u16 f2bf_rne(float f) {
    unsigned u = __float_as_uint(f);
    u += 0x7FFFu + ((u >> 16) & 1u);
    return (u16)(u >> 16);
}

__device__ __forceinline__ void split4(const float* __restrict__ src,
                                       u16* __restrict__ hi, u16* __restrict__ lo, int i) {
    const float4 v = ((const float4*)src)[i];
    float vv[4] = {v.x, v.y, v.z, v.w};
    u16 hh[4], ll[4];
#pragma unroll
    for (int j = 0; j < 4; ++j) {
        unsigned u = __float_as_uint(vv[j]);
        unsigned r = u + 0x7FFFu + ((u >> 16) & 1u);
        u16 hb = (u16)(r >> 16);
        float hf = __uint_as_float((unsigned)hb << 16);
        hh[j] = hb;
        ll[j] = f2bf_rne(vv[j] - hf);   // residual exact in fp32, then RNE
    }
    ushort4 h, l;
    h.x = hh[0]; h.y = hh[1]; h.z = hh[2]; h.w = hh[3];
    l.x = ll[0]; l.y = ll[1]; l.z = ll[2]; l.w = ll[3];
    ((ushort4*)hi)[i] = h;
    ((ushort4*)lo)[i] = l;
}

// one fused launch: x | w_sin | w_cos regions + zero-init of g
#define NX4  (17694720 / 4)
#define NW4  (23592960 / 4)
#define NG4  (9830400 / 4)
__global__ void split_all_kernel(const float* __restrict__ x,
                                 const float* __restrict__ wss,
                                 const float* __restrict__ wsc,
                                 u16* __restrict__ xh, u16* __restrict__ xl,
                                 u16* __restrict__ wh, u16* __restrict__ wl,
                                 float* __restrict__ g) {
    int i = blockIdx.x * 256 + threadIdx.x;
    if (i < NX4) {
        split4(x, xh, xl, i);
    } else if (i < NX4 + NW4) {
        split4(wss, wh, wl, i - NX4);
    } else if (i < NX4 + 2 * NW4) {
        int j = i - NX4 - NW4;
        split4(wsc, wh + (size_t)NFILT * KD, wl + (size_t)NFILT * KD, j);
    }
    if (i < NG4) {   // fold the g memset into this BW-bound pass
        float4 z; z.x = 0.f; z.y = 0.f; z.z = 0.f; z.w = 0.f;
        ((float4*)g)[i] = z;
    }
}

// ---------- async global->LDS, 16B per lane ----------
__device__ __forceinline__ void glds16(const u16* gp, __bf16* lp) {
    __builtin_amdgcn_global_load_lds(
        (const __attribute__((address_space(1))) void*)gp,
        (__attribute__((address_space(3))) void*)lp, 16, 0, 0);
}

// swizzled element offset within a [256][32] bf16 tile.
// 16B granule g of row r is XOR'd with (r>>1)&3 -> a wave's 64-lane
// ds_read_b128 spreads across all 32 banks at the 8-access minimum.
__device__ __forceinline__ int frag_off(int r, int fo) {
    return r * 32 + (((fo >> 3) ^ ((r >> 1) & 3)) << 3);
}

// ---------- bf16x3 split GEMM, 256x256 tile, BK=32, rolling pipeline ----
// C = Ah*Bh + Ah*Bl + Al*Bh   (32x32x16 MFMA, split-K=3, atomic accumulate)
// Per kt: 4 compute steps x 12 MFMA, one-step-ahead register pipeline:
// frag reads for step s+1 issue BEFORE the cluster of step s, so the DS
// drain overlaps the matrix pipe (each cluster's lgkmcnt is pre-satisfied).
// TWO barriers/kt (re-derived after the r5 race):
//   barrier#1: after vmcnt(4) -> ALL waves' A1(cur) landed; h1 reads follow.
//   barrier#2: after vmcnt(2) -> ALL waves' Bh,Bl,A0(kt+1) landed; the
//              next tile's first reads + trailing (h1,s1) cluster follow.
// A1(kt+1) stays in flight across the kt boundary (vmcnt never 0 mid-loop).
__global__ __launch_bounds__(512, 2) void gemm_split_kernel(
    const u16* __restrict__ xh, const u16* __restrict__ xl,
    const u16* __restrict__ wh, const u16* __restrict__ wl,
    float* __restrict__ g) {

    extern __shared__ char smem_c[];
    __bf16* const smem = (__bf16*)smem_c;
    // per dbuf (32768 elems): Ah +0 (h0 0..4096, h1 4096..8192) | Al +8192
    //                         Bh +16384 | Bl +24576

    const int tid = threadIdx.x;
    const int l   = tid & 63;
    const int w   = tid >> 6;

    // T1: bijective XCD swizzle (480 % 8 == 0)
    int bid = (int)blockIdx.x;
    bid = (bid & 7) * (160 * KSPLIT / 8) + (bid >> 3);
    const int ks = bid / 160;
    const int t  = bid % 160;
    const int m0 = (t / 20) * 256;       // 8 m-tiles (last is half-padded)
    const int n0 = (t % 20) * 256;       // 20 n-tiles
    const unsigned kb = (unsigned)ks * KSLICE;
    const bool mhalf = (m0 + 128 >= M_DIM);   // last m-tile: h1 rows all OOB

    // ---- staging geometry: lane-linear LDS dest, inverse-swizzled source ----
    const int rl  = w * 16 + (l >> 2);                     // row in 128-row half
    const int gsw = ((l & 3) ^ ((rl >> 1) & 3)) * 8;       // swizzled src granule
    const int sd  = w * 512 + l * 8;                       // dest = base + lane*16B

    int ar0 = m0 + rl;        if (ar0 > M_DIM - 1) ar0 = M_DIM - 1;  // clamp pad
    int ar1 = m0 + rl + 128;  if (ar1 > M_DIM - 1) ar1 = M_DIM - 1;
    const unsigned offA0 = (unsigned)ar0 * KD + kb + gsw;
    const unsigned offA1 = (unsigned)ar1 * KD + kb + gsw;
    const unsigned offB0 = (unsigned)(n0 + rl) * KD + kb + gsw;
    const unsigned offB1 = (unsigned)(n0 + rl + 128) * KD + kb + gsw;

    // stage units (2 glds16/thread each); issue order: Bh | Bl | A-h0 | A-h1
#define ST_BH(D,KO) do { __bf16* s_ = smem + (D)*32768;                 \
        glds16(wh + (offB0 + (KO)), s_ + 16384 + sd);                   \
        glds16(wh + (offB1 + (KO)), s_ + 20480 + sd); } while (0)
#define ST_BL(D,KO) do { __bf16* s_ = smem + (D)*32768;                 \
        glds16(wl + (offB0 + (KO)), s_ + 24576 + sd);                   \
        glds16(wl + (offB1 + (KO)), s_ + 28672 + sd); } while (0)
#define ST_A0(D,KO) do { __bf16* s_ = smem + (D)*32768;                 \
        glds16(xh + (offA0 + (KO)), s_ + 0     + sd);                   \
        glds16(xl + (offA0 + (KO)), s_ + 8192  + sd); } while (0)
#define ST_A1(D,KO) do { __bf16* s_ = smem + (D)*32768;                 \
        glds16(xh + (offA1 + (KO)), s_ + 4096  + sd);                   \
        glds16(xl + (offA1 + (KO)), s_ + 12288 + sd); } while (0)

    // ---- compute geometry: 8 waves = 2M x 4N; per-wave C = 128x64 ----
    const int rA = l & 31;
    const int kq = (l >> 5) * 8;
    const int wr = w >> 2;
    const int wc = w & 3;

    int aoff[2][2], boff[2][2];          // [mf][s] (h1 = +4096) / [nf][s]
#pragma unroll
    for (int mf = 0; mf < 2; ++mf)
#pragma unroll
        for (int s = 0; s < 2; ++s)
            aoff[mf][s] = frag_off(wr * 64 + mf * 32 + rA, s * 16 + kq);
#pragma unroll
    for (int nf = 0; nf < 2; ++nf)
#pragma unroll
        for (int s = 0; s < 2; ++s)
            boff[nf][s] = frag_off(wc * 64 + nf * 32 + rA, s * 16 + kq);

    f32x16 acc[4][2];
#pragma unroll
    for (int i = 0; i < 4; ++i)
#pragma unroll
        for (int j = 0; j < 2; ++j)
#pragma unroll
            for (int r = 0; r < 16; ++r)
                acc[i][j][r] = 0.f;

    // frag registers: B (both s), rolling A sets X/Y
    bf16x8 bh0[2], bl0[2], bh1[2], bl1[2];
    bf16x8 aXh[2], aXl[2], aYh[2], aYl[2];

#define RD_B(SB, S, H, L) do {                                          \
        H[0] = *(const bf16x8*)((SB) + 16384 + boff[0][S]);             \
        H[1] = *(const bf16x8*)((SB) + 16384 + boff[1][S]);             \
        L[0] = *(const bf16x8*)((SB) + 24576 + boff[0][S]);             \
        L[1] = *(const bf16x8*)((SB) + 24576 + boff[1][S]); } while (0)
#define RD_A(SB, HOFF, S, H, L) do {                                    \
        H[0] = *(const bf16x8*)((SB) + (HOFF) + aoff[0][S]);            \
        H[1] = *(const bf16x8*)((SB) + (HOFF) + aoff[1][S]);            \
        L[0] = *(const bf16x8*)((SB) + 8192 + (HOFF) + aoff[0][S]);     \
        L[1] = *(const bf16x8*)((SB) + 8192 + (HOFF) + aoff[1][S]); } while (0)

#define MFMA3(ACC, AH, AL, BH, BL)                                              \
    ACC = __builtin_amdgcn_mfma_f32_32x32x16_bf16(AH, BH, ACC, 0, 0, 0);        \
    ACC = __builtin_amdgcn_mfma_f32_32x32x16_bf16(AH, BL, ACC, 0, 0, 0);        \
    ACC = __builtin_amdgcn_mfma_f32_32x32x16_bf16(AL, BH, ACC, 0, 0, 0);

#define CLUSTER(AM, AH, AL, BH, BL) do {                                        \
        __builtin_amdgcn_s_setprio(1);                                          \
        MFMA3(acc[(AM) + 0][0], AH[0], AL[0], BH[0], BL[0]);                    \
        MFMA3(acc[(AM) + 0][1], AH[0], AL[0], BH[1], BL[1]);                    \
        MFMA3(acc[(AM) + 1][0], AH[1], AL[1], BH[0], BL[0]);                    \
        MFMA3(acc[(AM) + 1][1], AH[1], AL[1], BH[1], BL[1]);                    \
        __builtin_amdgcn_s_setprio(0);                                          \
    } while (0)

    // ---- prologue: stage k-tile 0 (Bh,Bl,A0,A1); A1 stays in flight ----
    ST_BH(0, 0); ST_BL(0, 0); ST_A0(0, 0); ST_A1(0, 0);
    asm volatile("s_waitcnt vmcnt(2)" ::: "memory");   // Bh,Bl,A0 landed
    __builtin_amdgcn_s_barrier();
    RD_B(smem, 0, bh0, bl0);             // step0 frags: B(s0), A-h0(s0)
    RD_A(smem, 0, 0, aXh, aXl);

    for (int kt = 0; kt < NT; ++kt) {
        const int cur = kt & 1;
        const __bf16* sb = smem + cur * 32768;
        const __bf16* sn = smem + (cur ^ 1) * 32768;
        const int ko = (kt + 1) * 32;
        const bool pf = (kt < NT - 1);

        // ---- step0: (h0,s0) on X; read-ahead B(s1), A-h0(s1); stage Bh,Bl ----
        if (pf) { ST_BH(cur ^ 1, ko); ST_BL(cur ^ 1, ko); }
        RD_B(sb, 1, bh1, bl1);
        RD_A(sb, 0, 1, aYh, aYl);
        __builtin_amdgcn_sched_barrier(0);
        CLUSTER(0, aXh, aXl, bh0, bl0);

        // ---- barrier #1: ALL waves' A1(cur) landed -> h1 region readable ----
        if (pf) { asm volatile("s_waitcnt vmcnt(4)" ::: "memory"); }
        else    { asm volatile("s_waitcnt vmcnt(0)" ::: "memory"); }
        __builtin_amdgcn_s_barrier();

        // ---- step1: (h0,s1) on Y; read-ahead A-h1(s0); stage A0,A1 ----
        if (pf) { ST_A0(cur ^ 1, ko); ST_A1(cur ^ 1, ko); }
        if (!mhalf) RD_A(sb, 4096, 0, aXh, aXl);
        __builtin_amdgcn_sched_barrier(0);
        CLUSTER(0, aYh, aYl, bh1, bl1);

        // ---- step2: (h1,s0) on X; read-ahead A-h1(s1) ----
        if (!mhalf) {
            RD_A(sb, 4096, 1, aYh, aYl);
            __builtin_amdgcn_sched_barrier(0);
            CLUSTER(2, aXh, aXl, bh0, bl0);
        }

        // ---- barrier #2 + step3: (h1,s1) on Y runs AFTER the kt-boundary
        //      barrier; the next kt's first read burst drains under it ----
        if (pf) {
            asm volatile("s_waitcnt vmcnt(2)" ::: "memory");  // Bh,Bl,A0(kt+1) landed
            __builtin_amdgcn_s_barrier();
            RD_B(sn, 0, bh0, bl0);
            RD_A(sn, 0, 0, aXh, aXl);
            __builtin_amdgcn_sched_barrier(0);
        }
        if (!mhalf) CLUSTER(2, aYh, aYl, bh1, bl1);
    }

    // ---- epilogue: 32x32 C/D layout col=l&31, row=(r&3)+8*(r>>2)+4*(l>>5) ----
    const int cb = (l >> 5) * 4;
    const int cc = l & 31;
#pragma unroll
    for (int am = 0; am < 4; ++am) {     // am = h*2 + mf
        const int rowb = m0 + (am >> 1) * 128 + wr * 64 + (am & 1) * 32;
        if (rowb < M_DIM) {              // whole 32-row frag in/out (1920%32==0)
#pragma unroll
            for (int nf = 0; nf < 2; ++nf) {
                const int col = n0 + wc * 64 + nf * 32 + cc;
                float* gp = g + (size_t)rowb * N_DIM + col;
#pragma unroll
                for (int r = 0; r < 16; ++r) {
                    const int ro = (r & 3) + 8 * (r >> 2) + cb;
                    atomicAdd(gp + (size_t)ro * N_DIM, acc[am][nf][r]);
                }
            }
        }
    }
#undef ST_BH
#undef ST_BL
#undef ST_A0
#undef ST_A1
#undef RD_B
#undef RD_A
#undef MFMA3
#undef CLUSTER
}

// ---------- depthwise temporal conv + energy, LDS-staged weights ----------
// block = one (b, 8-t-chunk, 256-filter chunk); thread = one filter.
// The 23-row g window is loaded into registers once and reused across the
// 8 t's (46 loads vs 256); the 32 KB weight LDS load amortizes 8x.
__global__ __launch_bounds__(256) void conv_energy_kernel(
    const float* __restrict__ g,
    const float* __restrict__ wts,
    const float* __restrict__ wtc,
    float* __restrict__ out) {

    __shared__ float wl_c[16][256];
    __shared__ float wl_s[16][256];

    const int tid = threadIdx.x;
    const int bid = blockIdx.x;          // 2400 = 8 * 30 * 10
    const int fc  = bid % 10;
    const int t8  = (bid / 10) % 30;
    const int b   = bid / 300;
    const int f0  = fc * 256;
    const int t0  = t8 * 8;

    // cooperative weight load: thread tid owns filter f0+tid's 16 taps
    {
        const float4* wrc = (const float4*)(wtc + (size_t)(f0 + tid) * 16);
        const float4* wrs = (const float4*)(wts + (size_t)(f0 + tid) * 16);
#pragma unroll
        for (int k4 = 0; k4 < 4; ++k4) {
            const float4 vc = wrc[k4];
            const float4 vs = wrs[k4];
            wl_c[k4 * 4 + 0][tid] = vc.x; wl_c[k4 * 4 + 1][tid] = vc.y;
            wl_c[k4 * 4 + 2][tid] = vc.z; wl_c[k4 * 4 + 3][tid] = vc.w;
            wl_s[k4 * 4 + 0][tid] = vs.x; wl_s[k4 * 4 + 1][tid] = vs.y;
            wl_s[k4 * 4 + 2][tid] = vs.z; wl_s[k4 * 4 + 3][tid] = vs.w;
        }
    }
    __syncthreads();

    const float* grow = g + (size_t)b * T_LEN * N_DIM + f0 + tid;
    float gsv[23], gcv[23];
#pragma unroll
    for (int r = 0; r < 23; ++r) {
        const int tt = t0 + r - PAD_L;
        if (tt >= 0 && tt < T_LEN) {     // block-uniform branch
            gsv[r] = grow[(size_t)tt * N_DIM];
            gcv[r] = grow[(size_t)tt * N_DIM + NFILT];
        } else {
            gsv[r] = 0.f; gcv[r] = 0.f;
        }
    }

    float* orow = out + (size_t)((b * T_LEN + t0) * NFILT) + f0 + tid;
#pragma unroll
    for (int tt = 0; tt < 8; ++tt) {
        float s = 0.f, c = 0.f;
#pragma unroll
        for (int j = 0; j < 16; ++j) {
            const float a  = wl_c[j][tid];
            const float bb = wl_s[j][tid];
            s += gsv[tt + j] * a + gcv[tt + j] * bb;
            c += gcv[tt + j] * a - gsv[tt + j] * bb;
        }
        orow[(size_t)tt * NFILT] = logf(sqrtf(s * s + c * c) + 1e-5f);
    }
}

extern "C" void kernel_launch(void* const* d_in, const int* in_sizes, int n_in,
                              void* d_out, int out_size, void* d_ws, size_t ws_size,
                              hipStream_t stream) {
    const float* x   = (const float*)d_in[0];  // (8,240,96,96)
    const float* wss = (const float*)d_in[1];  // (2560,96,96)
    const float* wsc = (const float*)d_in[2];  // (2560,96,96)
    const float* wts = (const float*)d_in[3];  // (2560,16)
    const float* wtc = (const float*)d_in[4];  // (2560,16)
    float* out = (float*)d_out;

    // workspace layout (bytes):
    //   xh: 35,389,440 | xl: 35,389,440 | wh: 94,371,840 | wl: 94,371,840 | g: 39,321,600
    char* ws = (char*)d_ws;
    u16*   xh  = (u16*)(ws);
    u16*   xl  = (u16*)(ws + 35389440);
    u16*   whi = (u16*)(ws + 70778880);
    u16*   wlo = (u16*)(ws + 165150720);
    float* g   = (float*)(ws + 259522560);

    static bool gemm_attr_set = false;
    if (!gemm_attr_set) {
        hipFuncSetAttribute(reinterpret_cast<const void*>(gemm_split_kernel),
                            hipFuncAttributeMaxDynamicSharedMemorySize, GEMM_LDS);
        gemm_attr_set = true;
    }

    const int ntot4 = NX4 + 2 * NW4;   // covers NG4 too (NG4 < NX4)
    split_all_kernel<<<(ntot4 + 255) / 256, 256, 0, stream>>>(x, wss, wsc, xh, xl, whi, wlo, g);

    gemm_split_kernel<<<160 * KSPLIT, 512, GEMM_LDS, stream>>>(xh, xl, whi, wlo, g);

    conv_energy_kernel<<<B_SZ * 30 * 10, 256, 0, stream>>>(g, wts, wtc, out);
}